// Round 2
// baseline (1269.538 us; speedup 1.0000x reference)
//
#include <hip/hip_runtime.h>
#include <math.h>

#define B_   32
#define C_   256
#define H_   80
#define W_   80
#define MID_ 64
#define HW_  (H_*W_)      // 6400
#define H2_  160
#define W2_  160
#define HW2_ (H2_*W2_)    // 25600
#define CSPLIT_ 8
#define CCHUNK_ (C_/CSPLIT_)   // 32 channels per thread in sample_kernel

// ---------------------------------------------------------------------------
// Kernel 0: transpose w1 [m][c] -> w1t [c][m] (64 KB, one-time, ~2 us).
// Needed so offsets_kernel can read weight rows with wave-UNIFORM contiguous
// addresses -> compiler emits s_load_dwordx16 (scalar pipe) instead of LDS.
// ---------------------------------------------------------------------------
__global__ __launch_bounds__(256) void transpose_w1_kernel(
    const float* __restrict__ w1, float* __restrict__ w1t)
{
    int idx = blockIdx.x * 256 + threadIdx.x;   // [0, C_*MID_)
    int m = idx & (MID_-1);
    int c = idx >> 6;
    w1t[idx] = w1[m*C_ + c];                     // coalesced write
}

// ---------------------------------------------------------------------------
// Kernel 1: fused 1x1 conv (C->MID) + relu + 1x1 conv (MID->8) + tanh
// CHANGED: no LDS. Weights are wave-uniform -> read from global with uniform
// addresses (w1t[c*64+m], w2[o*64+m], b2[o]); compiler scalarizes to s_load
// and the FMA takes the weight as the one allowed SGPR operand.
// Old version re-read 64KB of LDS per wave per pass = ~13 GB of LDS return
// traffic (~170 us chip-wide); scalar path removes that entirely.
// ---------------------------------------------------------------------------
__global__ __launch_bounds__(256) void offsets_kernel(
    const float* __restrict__ x, const float* __restrict__ w1t,
    const float* __restrict__ w2, const float* __restrict__ b2,
    float* __restrict__ off)
{
    int p  = blockIdx.x * 256 + threadIdx.x;   // global pixel id, exact grid
    int b  = p / HW_;
    int hw = p - b*HW_;
    const float* xp = x + (size_t)b*C_*HW_ + hw;

    float hid[MID_];
    #pragma unroll
    for (int m = 0; m < MID_; ++m) hid[m] = 0.f;

    for (int c = 0; c < C_; ++c) {
        float xv = xp[(size_t)c*HW_];          // coalesced across lanes
        const float* wr = w1t + c*MID_;        // wave-uniform address
        #pragma unroll
        for (int m = 0; m < MID_; ++m) hid[m] = fmaf(xv, wr[m], hid[m]);
    }
    #pragma unroll
    for (int m = 0; m < MID_; ++m) hid[m] = fmaxf(hid[m], 0.f);

    float* op = off + (size_t)b*8*HW_ + hw;
    #pragma unroll
    for (int o = 0; o < 8; ++o) {
        float acc = b2[o];                     // uniform -> s_load
        #pragma unroll
        for (int m = 0; m < MID_; ++m) acc = fmaf(hid[m], w2[o*MID_+m], acc);
        op[o*HW_] = tanhf(acc);                // coalesced store
    }
}

// ---------------------------------------------------------------------------
// Kernel 2: bilinear sample (border clamp, align-corners mapping) + 2x2
// pixel-shuffle. 8-way channel split: grid (800, 8), each thread owns one
// (b,h,w) pixel and a 32-channel slice.
// Rationale: gathers hit L2 (~200 cyc) since the per-channel window doesn't
// survive in L1 across the 25600B-stride channel loop; only TLP hides that.
// 6400 blocks -> occupancy VGPR-capped (~8 waves/SIMD), vs 3.1 grid-capped
// in the pre-split version. Setup (~150 VALU + 8 loads) amortizes over 32
// channels. Hot loop: block-uniform 64-bit base + 32-bit per-lane offsets.
// ---------------------------------------------------------------------------
__global__ __launch_bounds__(256) void sample_kernel(
    const float* __restrict__ x, const float* __restrict__ off,
    float* __restrict__ out)
{
    int p  = blockIdx.x * 256 + threadIdx.x;
    int b  = p / HW_;                 // uniform per block (25 blocks per batch)
    int hw = p - b*HW_;
    int h  = hw / W_;
    int w  = hw - h*W_;
    int c0 = blockIdx.y * CCHUNK_;    // uniform channel slice base

    const float* offp = off + (size_t)b*8*HW_ + hw;

    float wgt[4][4];
    int   ofs[4][4];
    #pragma unroll
    for (int k = 0; k < 4; ++k) {
        int i = k >> 1, j = k & 1;             // k = i*S + j
        float ox = offp[k*HW_];
        float oy = offp[(4+k)*HW_];
        float gx = -1.f + (2.f*(float)(2*w+j) + 1.f) * (1.f/(float)W2_);
        float gy = -1.f + (2.f*(float)(2*h+i) + 1.f) * (1.f/(float)H2_);
        float sx = gx + ox * (2.f/(float)W2_);
        float sy = gy + oy * (2.f/(float)H2_);
        float ix = (sx + 1.f) * 0.5f * (float)(W_-1);
        float iy = (sy + 1.f) * 0.5f * (float)(H_-1);
        ix = fminf(fmaxf(ix, 0.f), (float)(W_-1));
        iy = fminf(fmaxf(iy, 0.f), (float)(H_-1));
        float xf = floorf(ix), yf = floorf(iy);
        int   x0 = (int)xf,    y0 = (int)yf;
        float wx = ix - xf,    wy = iy - yf;
        int   x1 = min(x0+1, W_-1), y1 = min(y0+1, H_-1);
        wgt[k][0] = (1.f-wx)*(1.f-wy);
        wgt[k][1] = wx*(1.f-wy);
        wgt[k][2] = (1.f-wx)*wy;
        wgt[k][3] = wx*wy;
        ofs[k][0] = y0*W_ + x0;
        ofs[k][1] = y0*W_ + x1;
        ofs[k][2] = y1*W_ + x0;
        ofs[k][3] = y1*W_ + x1;
    }

    // Block-uniform 64-bit bases; everything per-lane below is 32-bit.
    const float* xq = x   + ((size_t)b*C_ + c0)*HW_;
    float*       oq = out + ((size_t)b*C_ + c0)*HW2_;
    int obase = (2*h)*W2_ + 2*w;      // per-lane, fits 32-bit

    #pragma unroll 2
    for (int ci = 0; ci < CCHUNK_; ++ci) {
        int xcb = ci*HW_;             // 32-bit channel offset
        float v[4];
        #pragma unroll
        for (int k = 0; k < 4; ++k) {
            v[k] = xq[xcb + ofs[k][0]]*wgt[k][0] + xq[xcb + ofs[k][1]]*wgt[k][1]
                 + xq[xcb + ofs[k][2]]*wgt[k][2] + xq[xcb + ofs[k][3]]*wgt[k][3];
        }
        int ob = ci*HW2_ + obase;     // 32-bit
        *reinterpret_cast<float2*>(oq + ob)        = make_float2(v[0], v[1]);
        *reinterpret_cast<float2*>(oq + ob + W2_)  = make_float2(v[2], v[3]);
    }
}

extern "C" void kernel_launch(void* const* d_in, const int* in_sizes, int n_in,
                              void* d_out, int out_size, void* d_ws, size_t ws_size,
                              hipStream_t stream) {
    const float* x  = (const float*)d_in[0];
    const float* w1 = (const float*)d_in[1];
    const float* w2 = (const float*)d_in[2];
    const float* b2 = (const float*)d_in[3];
    float* out = (float*)d_out;

    float* off = (float*)d_ws;                   // 8*B*H*W floats = 6.55 MB
    float* w1t = off + (size_t)8*B_*HW_;         // +64 KB transposed weights

    const int npix = B_*HW_;     // 204800 = 800 * 256 exactly

    transpose_w1_kernel<<<(C_*MID_)/256, 256, 0, stream>>>(w1, w1t);
    offsets_kernel<<<npix/256, 256, 0, stream>>>(x, w1t, w2, b2, off);
    dim3 grid2(npix/256, CSPLIT_);
    sample_kernel <<<grid2, 256, 0, stream>>>(x, off, out);
}

// Round 3
// 1103.196 us; speedup vs baseline: 1.1508x; 1.1508x over previous
//
#include <hip/hip_runtime.h>
#include <math.h>

#define B_   32
#define C_   256
#define H_   80
#define W_   80
#define MID_ 64
#define HW_  (H_*W_)      // 6400
#define H2_  160
#define W2_  160
#define HW2_ (H2_*W2_)    // 25600

#define TILE_H 4
#define WIN_H  8
#define WINSZ  (WIN_H*W_)     // 640 floats per channel window
#define NCH    8              // channels staged per chunk
#define TPB    (TILE_H*W_)    // 320 threads

// ---------------------------------------------------------------------------
// Kernel 0: transpose w1 [m][c] -> w1t [c][m] (64 KB, one-time, ~2 us) so the
// conv phase reads weight rows at wave-uniform contiguous addresses.
// ---------------------------------------------------------------------------
__global__ __launch_bounds__(256) void transpose_w1_kernel(
    const float* __restrict__ w1, float* __restrict__ w1t)
{
    int idx = blockIdx.x * 256 + threadIdx.x;   // [0, C_*MID_)
    int m = idx & (MID_-1);
    int c = idx >> 6;
    w1t[idx] = w1[m*C_ + c];
}

// ---------------------------------------------------------------------------
// FUSED kernel: conv->relu->conv->tanh offsets (in registers) + bilinear
// sample + 2x2 pixel shuffle, one pass, no off[] round-trip.
//
// Tile = 4 rows x 80 cols (full width). Block 320 threads, 1 thread/pixel.
// Grid 640 = 32 b x 20 tiles. Why full-width tiles: staging and conv reads
// are perfectly linear (no column halo, no per-row segmentation), and the
// bilinear x-taps clamp within [0,79] which is always resident.
//
// Window rows: |off|<1 (tanh) => tap jitter < 0.494 px. For tile start h0,
// needed input rows ⊂ [floor(0.9875*h0)-1, floor(0.9875*h0)+6]  (audited for
// all h0 in {0,4,...,76}), so y_lo = clamp(79*h0/80 - 1, 0, 72), 8-row window.
//
// Phase 2 per chunk (8 ch): stage 8x640 floats (1 float2/thread/ch, linear),
// then per ch: 16 ds_read_b32 (idx precomputed ONCE for all 256 ch) + 16 FMA
// + two float2 stores. All idx/wgt arrays unroll-constant indexed (registers).
// ---------------------------------------------------------------------------
__global__ __launch_bounds__(TPB) void fused_kernel(
    const float* __restrict__ x, const float* __restrict__ w1t,
    const float* __restrict__ w2, const float* __restrict__ b2,
    float* __restrict__ out)
{
    __shared__ float xs[NCH * WINSZ];   // 8*640*4B = 20.5 KB

    const int blk = blockIdx.x;             // 0..639
    const int b   = blk / (H_/TILE_H);      // image
    const int t   = blk % (H_/TILE_H);      // tile row group
    const int h0  = t * TILE_H;
    const int ty  = threadIdx.x / W_;       // 0..3
    const int tx  = threadIdx.x - ty*W_;    // 0..79
    const int h   = h0 + ty;
    const int w   = tx;
    const int hw  = h*W_ + w;

    int y_lo = (79*h0)/80 - 1;              // floor(0.9875*h0) - 1
    if (y_lo < 0) y_lo = 0;
    if (y_lo > H_ - WIN_H) y_lo = H_ - WIN_H;   // clamp to 72

    // ---------------- Phase 1: offsets (per-pixel, registers) --------------
    const float* xp = x + (size_t)b*C_*HW_ + hw;

    float hid[MID_];
    #pragma unroll
    for (int m = 0; m < MID_; ++m) hid[m] = 0.f;

    #pragma unroll 4
    for (int c = 0; c < C_; ++c) {
        float xv = xp[c*HW_];               // coalesced (full-row lanes)
        const float* wr = w1t + c*MID_;     // wave-uniform address
        #pragma unroll
        for (int m = 0; m < MID_; ++m) hid[m] = fmaf(xv, wr[m], hid[m]);
    }
    #pragma unroll
    for (int m = 0; m < MID_; ++m) hid[m] = fmaxf(hid[m], 0.f);

    float offv[8];
    #pragma unroll
    for (int o = 0; o < 8; ++o) {
        float acc = b2[o];
        #pragma unroll
        for (int m = 0; m < MID_; ++m) acc = fmaf(hid[m], w2[o*MID_+m], acc);
        offv[o] = tanhf(acc);
    }

    // ------------- bilinear setup: 16 weights + 16 LDS offsets -------------
    float wgt[16];
    int   idx[16];
    #pragma unroll
    for (int k = 0; k < 4; ++k) {
        int i = k >> 1, j = k & 1;
        float gx = -1.f + (2.f*(float)(2*w+j) + 1.f) * (1.f/(float)W2_);
        float gy = -1.f + (2.f*(float)(2*h+i) + 1.f) * (1.f/(float)H2_);
        float sx = gx + offv[k]   * (2.f/(float)W2_);
        float sy = gy + offv[4+k] * (2.f/(float)H2_);
        float ix = (sx + 1.f) * 0.5f * (float)(W_-1);
        float iy = (sy + 1.f) * 0.5f * (float)(H_-1);
        ix = fminf(fmaxf(ix, 0.f), (float)(W_-1));
        iy = fminf(fmaxf(iy, 0.f), (float)(H_-1));
        float xf = floorf(ix), yf = floorf(iy);
        int   x0 = (int)xf,    y0 = (int)yf;
        float wx = ix - xf,    wy = iy - yf;
        int   x1 = min(x0+1, W_-1), y1 = min(y0+1, H_-1);
        int   ly0 = y0 - y_lo,      ly1 = y1 - y_lo;   // in [0, WIN_H)
        wgt[k*4+0] = (1.f-wx)*(1.f-wy);
        wgt[k*4+1] = wx*(1.f-wy);
        wgt[k*4+2] = (1.f-wx)*wy;
        wgt[k*4+3] = wx*wy;
        idx[k*4+0] = ly0*W_ + x0;
        idx[k*4+1] = ly0*W_ + x1;
        idx[k*4+2] = ly1*W_ + x0;
        idx[k*4+3] = ly1*W_ + x1;
    }

    // ---------------- Phase 2: chunked LDS sampling ------------------------
    const float* xgb = x + (size_t)b*C_*HW_ + y_lo*W_;   // + c*HW_ + j
    const int ob_off = (2*h)*W2_ + 2*w;

    for (int c0 = 0; c0 < C_; c0 += NCH) {
        __syncthreads();                    // previous chunk fully consumed
        #pragma unroll
        for (int ch = 0; ch < NCH; ++ch) {
            // 640 floats = 320 threads x 1 float2, linear: (y_lo+r)*80+c = y_lo*80+j
            float2 s = *reinterpret_cast<const float2*>(
                xgb + (size_t)(c0+ch)*HW_ + 2*threadIdx.x);
            *reinterpret_cast<float2*>(&xs[ch*WINSZ + 2*threadIdx.x]) = s;
        }
        __syncthreads();

        #pragma unroll
        for (int ch = 0; ch < NCH; ++ch) {
            const float* cs = &xs[ch*WINSZ];
            float v0 = cs[idx[0]] *wgt[0]  + cs[idx[1]] *wgt[1]
                     + cs[idx[2]] *wgt[2]  + cs[idx[3]] *wgt[3];
            float v1 = cs[idx[4]] *wgt[4]  + cs[idx[5]] *wgt[5]
                     + cs[idx[6]] *wgt[6]  + cs[idx[7]] *wgt[7];
            float v2 = cs[idx[8]] *wgt[8]  + cs[idx[9]] *wgt[9]
                     + cs[idx[10]]*wgt[10] + cs[idx[11]]*wgt[11];
            float v3 = cs[idx[12]]*wgt[12] + cs[idx[13]]*wgt[13]
                     + cs[idx[14]]*wgt[14] + cs[idx[15]]*wgt[15];
            float* ob = out + (size_t)(b*C_ + c0 + ch)*HW2_ + ob_off;
            *reinterpret_cast<float2*>(ob)       = make_float2(v0, v1);
            *reinterpret_cast<float2*>(ob + W2_) = make_float2(v2, v3);
        }
    }
}

extern "C" void kernel_launch(void* const* d_in, const int* in_sizes, int n_in,
                              void* d_out, int out_size, void* d_ws, size_t ws_size,
                              hipStream_t stream) {
    const float* x  = (const float*)d_in[0];
    const float* w1 = (const float*)d_in[1];
    const float* w2 = (const float*)d_in[2];
    const float* b2 = (const float*)d_in[3];
    float* out = (float*)d_out;
    float* w1t = (float*)d_ws;            // 64 KB transposed weights

    transpose_w1_kernel<<<(C_*MID_)/256, 256, 0, stream>>>(w1, w1t);

    const int nblk = B_ * (H_/TILE_H);    // 32 * 20 = 640
    fused_kernel<<<nblk, TPB, 0, stream>>>(x, w1t, w2, b2, out);
}